// Round 13
// baseline (1006.365 us; speedup 1.0000x reference)
//
#include <hip/hip_runtime.h>
#include <hip/hip_bf16.h>

typedef unsigned short u16;
typedef unsigned int u32;
typedef __bf16 bf16x8 __attribute__((ext_vector_type(8)));
typedef float f32x16 __attribute__((ext_vector_type(16)));
typedef float f32x4 __attribute__((ext_vector_type(4)));
typedef u32 u32x4 __attribute__((ext_vector_type(4)));

#define NN 100000
#define PROC_BLK 205
#define ENC_BLK 51
#define PROC_TILES 12500   // 400000 / 32
#define ENC_TILES 3125     // 100000 / 32
#define TILES_PER_T 3125
#define LN2F 0.69314718055994530942f
#define LOG2EF 1.44269504088896340736f
#define CSTRIDE 1284   // floats per net in cprep (16B-aligned stride)

__device__ __forceinline__ u16 f2bf(float f) {
  u32 u = __float_as_uint(f);
  u32 r = u + 0x7fffu + ((u >> 16) & 1u);   // RNE
  return (u16)(r >> 16);
}

// packed 2x f32 -> bf16 (RNE) via v_cvt_pk_bf16_f32
__device__ __forceinline__ u32 pk2(float a, float b) {
  float2 f2; f2.x = a; f2.y = b;
  __hip_bfloat162 h = __float22bfloat162_rn(f2);
  u32 r;
  __builtin_memcpy(&r, &h, 4);
  return r;
}

// log2(1 + 2^xp): the whole ssp after prep-time folds (log2e folded into
// gamma/beta; the ln2*(L-1) affine folded into next-stage W/b or wv/C0).
__device__ __forceinline__ float l2p1e(float xp) {
  return __builtin_amdgcn_logf(1.0f + __builtin_amdgcn_exp2f(xp));
}

// Build the LDS-image of W^T with the XOR-swizzle baked in (verified layout):
// per matrix m (32768 B): byte[r*256 + c*2(+1)] where storage col c holds
// logical k = ((c>>3) ^ (r&15))*8 + (c&7), value = bf16(W'[m][k][r]).
// W' = W for stage 0, ln2*W for stages 1,2 (ssp affine fold).
// Blocks 384/385 build the folded constant block cprep per net:
//   [s*3+0][j] = b'  (b - ln2*colsum(W) for s>=1)
//   [s*3+1][j] = gamma * log2e
//   [s*3+2][j] = beta  * log2e
//   [9][j]     = ln2 * wv
//   [1280]     = C0 = -ln2 * sum(wv)
__global__ void prep_kernel(const float* __restrict__ pW, const float* __restrict__ eW,
                            const float* __restrict__ pb, const float* __restrict__ pg,
                            const float* __restrict__ pbt,
                            const float* __restrict__ eb, const float* __restrict__ eg,
                            const float* __restrict__ ebt,
                            const float* __restrict__ wp, const float* __restrict__ we,
                            const float* __restrict__ bp, const float* __restrict__ be,
                            u16* __restrict__ wt, float* __restrict__ cprep,
                            float* __restrict__ out) {
  int bx = blockIdx.x;
  int t = threadIdx.x;
  if (bx < 384) {
    int idx = bx * 256 + t;
    int m = idx >> 14;             // 0..5 (0-2 proc, 3-5 enc)
    int within = idx & 16383;
    int r = within >> 7;           // output col j (row of W^T)
    int c = within & 127;          // storage column
    int k = (((c >> 3) ^ (r & 15)) << 3) | (c & 7);
    const float* src = (m < 3) ? pW : eW;
    int ms = (m < 3) ? m : m - 3;
    float w = src[ms * 16384 + k * 128 + r];
    if (ms >= 1) w *= LN2F;
    wt[idx] = f2bf(w);
    if (idx < 4096) out[idx] = bp[0] + be[0];
  } else {
    int net = bx - 384;
    const float* W  = net ? eW : pW;
    const float* b  = net ? eb : pb;
    const float* g  = net ? eg : pg;
    const float* bt = net ? ebt : pbt;
    const float* wv = net ? we : wp;
    float* cp = cprep + net * CSTRIDE;
    if (t < 128) {
      int j = t;
      #pragma unroll
      for (int s = 0; s < 3; ++s) {
        float bb = b[s * 128 + j];
        if (s >= 1) {
          float cs = 0.f;
          #pragma unroll 8
          for (int k = 0; k < 128; ++k) cs += W[s * 16384 + k * 128 + j];
          bb -= LN2F * cs;
        }
        cp[(s * 3 + 0) * 128 + j] = bb;
        cp[(s * 3 + 1) * 128 + j] = g[s * 128 + j] * LOG2EF;
        cp[(s * 3 + 2) * 128 + j] = bt[s * 128 + j] * LOG2EF;
      }
      cp[9 * 128 + j] = LN2F * wv[j];
    }
    if (t == 0) {
      float ssum = 0.f;
      #pragma unroll 8
      for (int j = 0; j < 128; ++j) ssum += wv[j];
      cp[1280] = -LN2F * ssum;
    }
  }
}

// PERSISTENT-W kernel: 256 blocks (205 proc / 51 enc) x 512 threads
// (8 waves), 1 block/CU (99 KB LDS forces it).
// __launch_bounds__(512, 1): R12's (512,2) was interpreted by hipcc with
// CUDA semantics (min 2 BLOCKS/CU -> 16 waves/CU -> 128-reg clamp ->
// 468 MB spill, VGPR_Count=128 was the smoking gun). With min 1 block the
// budget is >=256 regs under either interpretation; demand ~150-170 fits
// clean. All 3 stage-W images -> LDS once; each wave grid-strides
// independent 32-row tiles: zero barriers / W-restaging in steady state.
__global__ __launch_bounds__(512, 1)
void mlp_kernel(const float* __restrict__ x_proc, const float* __restrict__ x_enc,
                const u16* __restrict__ wt, const float* __restrict__ cprep,
                const int* __restrict__ batch, float* __restrict__ out) {
  __shared__ __align__(16) unsigned char wlds[98304];  // 3 stages x 32KB
  __shared__ f32x4 cball[10][32];
  __shared__ float c0s;

  const bool is_proc = blockIdx.x < PROC_BLK;
  const int bid2 = is_proc ? blockIdx.x : blockIdx.x - PROC_BLK;
  const float* x = is_proc ? x_proc : x_enc;
  const unsigned char* wgb = (const unsigned char*)(is_proc ? wt : wt + 49152);
  const float* cp = cprep + (is_proc ? 0 : CSTRIDE);

  const int tid = threadIdx.x;

  // ---- one-time: 96KB W image + constants -> LDS ----
  #pragma unroll
  for (int i = 0; i < 12; ++i) {
    int off = i * 8192 + tid * 16;
    *(u32x4*)(wlds + off) = *(const u32x4*)(wgb + off);
  }
  if (tid < 320) ((f32x4*)cball)[tid] = *(const f32x4*)(cp + tid * 4);
  if (tid == 0) c0s = cp[1280];
  __syncthreads();   // the only barrier in the kernel

  const int lane = tid & 63;
  const int wid = tid >> 6;            // 0..7
  const int l31 = lane & 31;
  const u32 hi = (u32)(lane >> 5);

  const int ntiles = is_proc ? PROC_TILES : ENC_TILES;
  const int wslots = (is_proc ? PROC_BLK : ENC_BLK) * 8;

  for (int tile = bid2 * 8 + wid; tile < ntiles; tile += wslots) {
    const int grow = tile * 32 + l31;   // exact tiling: always in range

    // ---- x -> bf16 fragments (global -> reg) ----
    const float* xr = x + (size_t)grow * 128 + (int)hi * 8;
    bf16x8 bfr[8];
    {
      f32x4 a[16];
      #pragma unroll
      for (int ks = 0; ks < 8; ++ks) {
        a[2 * ks]     = *(const f32x4*)(xr + ks * 16);
        a[2 * ks + 1] = *(const f32x4*)(xr + ks * 16 + 4);
      }
      #pragma unroll
      for (int ks = 0; ks < 8; ++ks) {
        u32x4 tq;
        tq.x = pk2(a[2 * ks][0], a[2 * ks][1]);
        tq.y = pk2(a[2 * ks][2], a[2 * ks][3]);
        tq.z = pk2(a[2 * ks + 1][0], a[2 * ks + 1][1]);
        tq.w = pk2(a[2 * ks + 1][2], a[2 * ks + 1][3]);
        bfr[ks] = __builtin_bit_cast(bf16x8, tq);
      }
    }

    float pfin = 0.0f;

    #pragma unroll
    for (int s = 0; s < 3; ++s) {
      const unsigned char* wsb = wlds + s * 32768;

      // acc init = folded bias b'
      f32x16 acc[4];
      #pragma unroll
      for (int jf = 0; jf < 4; ++jf)
        #pragma unroll
        for (int q = 0; q < 4; ++q) {
          f32x4 b4 = cball[s * 3 + 0][jf * 8 + 2 * q + (int)hi];
          acc[jf][4 * q + 0] = b4[0];
          acc[jf][4 * q + 1] = b4[1];
          acc[jf][4 * q + 2] = b4[2];
          acc[jf][4 * q + 3] = b4[3];
        }

      #pragma unroll
      for (int ks = 0; ks < 8; ++ks) {
        int aoff = l31 * 256 + (((2 * ks + (int)hi) ^ (l31 & 15)) << 4);
        #pragma unroll
        for (int jf = 0; jf < 4; ++jf) {
          const bf16x8 afrag = *(const bf16x8*)(const void*)(wsb + jf * 8192 + aoff);
          acc[jf] = __builtin_amdgcn_mfma_f32_32x32x16_bf16(afrag, bfr[ks], acc[jf], 0, 0, 0);
        }
      }
      // lane holds z[row][j] (incl. bias), j = jf*32 + 8q + 4hi + e

      // LN stats
      float s1 = 0.f, s2 = 0.f;
      #pragma unroll
      for (int jf = 0; jf < 4; ++jf) {
        float p1 = 0.f, p2 = 0.f;
        #pragma unroll
        for (int e = 0; e < 16; ++e) {
          float v = acc[jf][e];
          p1 += v;
          p2 = __builtin_fmaf(v, v, p2);
        }
        s1 += p1; s2 += p2;
      }
      s1 += __shfl_xor(s1, 32, 64);
      s2 += __shfl_xor(s2, 32, 64);
      float mean = s1 * 0.0078125f;
      float var = s2 * 0.0078125f - mean * mean;
      float rstd = rsqrtf(var + 1e-5f);
      float nmr = -mean * rstd;

      if (s < 2) {
        // normalize + ssp-core in ks-order -> next-stage fragments
        #pragma unroll
        for (int ks = 0; ks < 8; ++ks) {
          int jf = ks >> 1, q0 = (ks & 1) << 1;
          uint2 wq[2];
          #pragma unroll
          for (int qq = 0; qq < 2; ++qq) {
            int q = q0 + qq;
            f32x4 g4 = cball[s * 3 + 1][jf * 8 + 2 * q + (int)hi];
            f32x4 t4 = cball[s * 3 + 2][jf * 8 + 2 * q + (int)hi];
            float r0 = l2p1e((acc[jf][4 * q + 0] * rstd + nmr) * g4[0] + t4[0]);
            float r1 = l2p1e((acc[jf][4 * q + 1] * rstd + nmr) * g4[1] + t4[1]);
            float r2 = l2p1e((acc[jf][4 * q + 2] * rstd + nmr) * g4[2] + t4[2]);
            float r3 = l2p1e((acc[jf][4 * q + 3] * rstd + nmr) * g4[3] + t4[3]);
            wq[qq].x = pk2(r0, r1);
            wq[qq].y = pk2(r2, r3);
          }
          // exchange across lane pair -> next-stage B-fragment
          u32 sx = hi ? wq[0].x : wq[1].x;
          u32 sy = hi ? wq[0].y : wq[1].y;
          u32 rx = (u32)__shfl_xor((int)sx, 32, 64);
          u32 ry = (u32)__shfl_xor((int)sy, 32, 64);
          u32x4 tq;
          tq.x = hi ? rx : wq[0].x;       // h=0 quad (j offset 0..3)
          tq.y = hi ? ry : wq[0].y;
          tq.z = hi ? wq[1].x : rx;       // h=1 quad (j offset 4..7)
          tq.w = hi ? wq[1].y : ry;
          bfr[ks] = __builtin_bit_cast(bf16x8, tq);
        }
      } else {
        // final stage: fused projection with folded wv' (= ln2*wv)
        float p = 0.f;
        #pragma unroll
        for (int jf = 0; jf < 4; ++jf)
          #pragma unroll
          for (int q = 0; q < 4; ++q) {
            f32x4 g4 = cball[7][jf * 8 + 2 * q + (int)hi];
            f32x4 t4 = cball[8][jf * 8 + 2 * q + (int)hi];
            f32x4 w4 = cball[9][jf * 8 + 2 * q + (int)hi];
            #pragma unroll
            for (int e = 0; e < 4; ++e) {
              float v = l2p1e((acc[jf][4 * q + e] * rstd + nmr) * g4[e] + t4[e]);
              p = __builtin_fmaf(v, w4[e], p);
            }
          }
        pfin = p;
      }
    }

    // ---- segment sum ----
    pfin += __shfl_xor(pfin, 32, 64);   // combine the two j-halves
    pfin += c0s;                        // per-row constant from ssp fold
    int cell;
    if (is_proc) {
      int tt = tile / TILES_PER_T;      // tiles never straddle T
      cell = tt * 1024 + batch[grow - tt * NN];
    } else {
      cell = batch[grow];
    }
    // batch sorted -> cells monotone within the 32 consecutive rows
    int ca = __shfl(cell, 0, 32);
    int cz = __shfl(cell, 31, 32);
    if (ca == cz) {
      float r = pfin;
      #pragma unroll
      for (int off = 1; off < 32; off <<= 1) r += __shfl_xor(r, off, 64);
      if (hi == 0) {
        if (is_proc) {
          if (l31 == 0) atomicAdd(out + ca, r);
        } else {
          if (l31 < 4) atomicAdd(out + l31 * 1024 + ca, r);  // enc: all 4 t
        }
      }
    } else if (hi == 0) {
      if (is_proc) {
        atomicAdd(out + cell, pfin);
      } else {
        #pragma unroll
        for (int t2 = 0; t2 < 4; ++t2) atomicAdd(out + t2 * 1024 + cell, pfin);
      }
    }
  }
}

extern "C" void kernel_launch(void* const* d_in, const int* in_sizes, int n_in,
                              void* d_out, int out_size, void* d_ws, size_t ws_size,
                              hipStream_t stream) {
  const float* x_proc = (const float*)d_in[0];
  const float* x_enc  = (const float*)d_in[1];
  const int*   batch  = (const int*)d_in[2];
  const float* pW  = (const float*)d_in[3];
  const float* pb  = (const float*)d_in[4];
  const float* pg  = (const float*)d_in[5];
  const float* pbt = (const float*)d_in[6];
  const float* eW  = (const float*)d_in[7];
  const float* eb  = (const float*)d_in[8];
  const float* eg  = (const float*)d_in[9];
  const float* ebt = (const float*)d_in[10];
  const float* wp  = (const float*)d_in[11];
  const float* bp  = (const float*)d_in[12];
  const float* we  = (const float*)d_in[13];
  const float* be  = (const float*)d_in[14];

  float* out = (float*)d_out;
  u16* wt_ws = (u16*)d_ws;                       // 196608 B swizzled W images
  float* cprep = (float*)((char*)d_ws + 196608); // 2*CSTRIDE floats of folded consts

  prep_kernel<<<386, 256, 0, stream>>>(pW, eW, pb, pg, pbt, eb, eg, ebt,
                                       wp, we, bp, be, wt_ws, cprep, out);
  mlp_kernel<<<PROC_BLK + ENC_BLK, 512, 0, stream>>>(
      x_proc, x_enc, wt_ws, cprep, batch, out);
}

// Round 14
// 137.152 us; speedup vs baseline: 7.3376x; 7.3376x over previous
//
#include <hip/hip_runtime.h>
#include <hip/hip_bf16.h>

typedef unsigned short u16;
typedef unsigned int u32;
typedef __bf16 bf16x8 __attribute__((ext_vector_type(8)));
typedef float f32x16 __attribute__((ext_vector_type(16)));
typedef float f32x4 __attribute__((ext_vector_type(4)));
typedef float f32x2 __attribute__((ext_vector_type(2)));
typedef u32 u32x4 __attribute__((ext_vector_type(4)));

// pair views for packed (v_pk_*_f32) math
typedef struct { f32x2 h[2]; } f32x4p;
typedef struct { f32x2 h[8]; } f32x16p;

typedef __attribute__((address_space(1))) const u32 glb_u32;
typedef __attribute__((address_space(3))) u32 lds_u32;

#define NN 100000
#define NPROC_BLOCKS 3125
#define NENC_BLOCKS 782
#define LN2F 0.69314718055994530942f
#define LOG2EF 1.44269504088896340736f
#define CSTRIDE 1284   // floats per net in cprep (16B-aligned stride)

__device__ __forceinline__ u16 f2bf(float f) {
  u32 u = __float_as_uint(f);
  u32 r = u + 0x7fffu + ((u >> 16) & 1u);   // RNE
  return (u16)(r >> 16);
}

// packed 2x f32 -> bf16 (RNE) via v_cvt_pk_bf16_f32
__device__ __forceinline__ u32 pk2(float a, float b) {
  float2 f2; f2.x = a; f2.y = b;
  __hip_bfloat162 h = __float22bfloat162_rn(f2);
  u32 r;
  __builtin_memcpy(&r, &h, 4);
  return r;
}

// log2(1 + 2^xp): the whole ssp after prep-time folds (log2e folded into
// gamma/beta; the ln2*(L-1) affine folded into next-stage W/b or wv/C0).
__device__ __forceinline__ float l2p1e(float xp) {
  return __builtin_amdgcn_logf(1.0f + __builtin_amdgcn_exp2f(xp));
}

// Build the LDS-image of W^T with the XOR-swizzle baked in (verified layout):
// per matrix m (32768 B): byte[r*256 + c*2(+1)] where storage col c holds
// logical k = ((c>>3) ^ (r&15))*8 + (c&7), value = bf16(W'[m][k][r]).
// W' = W for stage 0, ln2*W for stages 1,2 (ssp affine fold).
// Blocks 384/385 build the folded constant block cprep per net:
//   [s*3+0][j] = b'  (b - ln2*colsum(W) for s>=1)
//   [s*3+1][j] = gamma * log2e
//   [s*3+2][j] = beta  * log2e
//   [9][j]     = ln2 * wv
//   [1280]     = C0 = -ln2 * sum(wv)
__global__ void prep_kernel(const float* __restrict__ pW, const float* __restrict__ eW,
                            const float* __restrict__ pb, const float* __restrict__ pg,
                            const float* __restrict__ pbt,
                            const float* __restrict__ eb, const float* __restrict__ eg,
                            const float* __restrict__ ebt,
                            const float* __restrict__ wp, const float* __restrict__ we,
                            const float* __restrict__ bp, const float* __restrict__ be,
                            u16* __restrict__ wt, float* __restrict__ cprep,
                            float* __restrict__ out) {
  int bx = blockIdx.x;
  int t = threadIdx.x;
  if (bx < 384) {
    int idx = bx * 256 + t;
    int m = idx >> 14;             // 0..5 (0-2 proc, 3-5 enc)
    int within = idx & 16383;
    int r = within >> 7;           // output col j (row of W^T)
    int c = within & 127;          // storage column
    int k = (((c >> 3) ^ (r & 15)) << 3) | (c & 7);
    const float* src = (m < 3) ? pW : eW;
    int ms = (m < 3) ? m : m - 3;
    float w = src[ms * 16384 + k * 128 + r];
    if (ms >= 1) w *= LN2F;
    wt[idx] = f2bf(w);
    if (idx < 4096) out[idx] = bp[0] + be[0];
  } else {
    int net = bx - 384;
    const float* W  = net ? eW : pW;
    const float* b  = net ? eb : pb;
    const float* g  = net ? eg : pg;
    const float* bt = net ? ebt : pbt;
    const float* wv = net ? we : wp;
    float* cp = cprep + net * CSTRIDE;
    if (t < 128) {
      int j = t;
      #pragma unroll
      for (int s = 0; s < 3; ++s) {
        float bb = b[s * 128 + j];
        if (s >= 1) {
          float cs = 0.f;
          #pragma unroll 8
          for (int k = 0; k < 128; ++k) cs += W[s * 16384 + k * 128 + j];
          bb -= LN2F * cs;
        }
        cp[(s * 3 + 0) * 128 + j] = bb;
        cp[(s * 3 + 1) * 128 + j] = g[s * 128 + j] * LOG2EF;
        cp[(s * 3 + 2) * 128 + j] = bt[s * 128 + j] * LOG2EF;
      }
      cp[9 * 128 + j] = LN2F * wv[j];
    }
    if (t == 0) {
      float ssum = 0.f;
      #pragma unroll 8
      for (int j = 0; j < 128; ++j) ssum += wv[j];
      cp[1280] = -LN2F * ssum;
    }
  }
}

// R11 structure (best, 140.1us) + packed-f32 (v_pk_*_f32) rewrite of the
// element-wise hot loops: LN stats, normalize affine, final affine --
// halves their scalar fma/add count (~11-15% of the VALU pipe, which at
// 47% busy is the bottleneck). Transcendentals remain scalar.
// R13 post-mortem: persistent-W abandoned (hipcc pins 512-thr+AGPR
// kernels at 128 arch VGPRs regardless of launch_bounds).
__global__ __launch_bounds__(256, 3)
void mlp_kernel(const float* __restrict__ x_proc, const float* __restrict__ x_enc,
                const u16* __restrict__ wt, const float* __restrict__ cprep,
                const int* __restrict__ batch, float* __restrict__ out) {
  __shared__ __align__(16) unsigned char wbuf[32768];
  __shared__ f32x4 cball[10][32];
  __shared__ float c0s;

  const bool is_proc = blockIdx.x < NPROC_BLOCKS;
  const int bid2 = is_proc ? blockIdx.x : blockIdx.x - NPROC_BLOCKS;
  const float* x = is_proc ? x_proc : x_enc;
  const unsigned char* wgb = (const unsigned char*)(is_proc ? wt : wt + 49152);
  const float* cp = cprep + (is_proc ? 0 : CSTRIDE);
  const int nrows = is_proc ? 400000 : 100000;

  const int tid = threadIdx.x;
  const int lane = tid & 63;
  const int wid = tid >> 6;
  const int l31 = lane & 31;
  const u32 hi = (u32)(lane >> 5);
  const int brow = bid2 * 128;

  // async W stage loader: linear image, dest = wave-uniform base + lane*16
  auto issue_w = [&](int s_) {
    #pragma unroll
    for (int i = 0; i < 8; ++i) {
      const unsigned char* gp = wgb + s_ * 32768 + i * 4096 + tid * 16;
      unsigned char* lp = wbuf + i * 4096 + wid * 1024;
      __builtin_amdgcn_global_load_lds((const glb_u32*)(const void*)gp,
                                       (lds_u32*)(void*)lp, 16, 0, 0);
    }
  };

  issue_w(0);   // latency hides under x load + cvt below

  // folded constants -> LDS
  for (int i = tid; i < 320; i += 256)
    ((f32x4*)cball)[i] = *(const f32x4*)(cp + i * 4);
  if (tid == 0) c0s = cp[1280];

  // x -> bf16 fragments (global -> reg, no LDS), single round
  const int rloc = wid * 32 + l31;
  const int grow = brow + rloc;
  const float* xr = x + (size_t)((grow < nrows) ? grow : (nrows - 1)) * 128 + (int)hi * 8;
  bf16x8 bfr[8];
  {
    f32x4 a[16];
    #pragma unroll
    for (int ks = 0; ks < 8; ++ks) {
      a[2 * ks]     = *(const f32x4*)(xr + ks * 16);
      a[2 * ks + 1] = *(const f32x4*)(xr + ks * 16 + 4);
    }
    #pragma unroll
    for (int ks = 0; ks < 8; ++ks) {
      u32x4 tq;
      tq.x = pk2(a[2 * ks][0], a[2 * ks][1]);
      tq.y = pk2(a[2 * ks][2], a[2 * ks][3]);
      tq.z = pk2(a[2 * ks + 1][0], a[2 * ks + 1][1]);
      tq.w = pk2(a[2 * ks + 1][2], a[2 * ks + 1][3]);
      bfr[ks] = __builtin_bit_cast(bf16x8, tq);
    }
  }

  float pfin = 0.0f;

  #pragma unroll
  for (int s = 0; s < 3; ++s) {
    __syncthreads();   // W(s) resident (vmcnt drained); covers cball at s=0

    // acc init = folded bias b'
    f32x16 acc[4];
    #pragma unroll
    for (int jf = 0; jf < 4; ++jf)
      #pragma unroll
      for (int q = 0; q < 4; ++q) {
        f32x4 b4 = cball[s * 3 + 0][jf * 8 + 2 * q + (int)hi];
        acc[jf][4 * q + 0] = b4[0];
        acc[jf][4 * q + 1] = b4[1];
        acc[jf][4 * q + 2] = b4[2];
        acc[jf][4 * q + 3] = b4[3];
      }

    #pragma unroll
    for (int ks = 0; ks < 8; ++ks) {
      int aoff = l31 * 256 + (((2 * ks + (int)hi) ^ (l31 & 15)) << 4);
      #pragma unroll
      for (int jf = 0; jf < 4; ++jf) {
        const bf16x8 afrag = *(const bf16x8*)(const void*)(wbuf + jf * 8192 + aoff);
        acc[jf] = __builtin_amdgcn_mfma_f32_32x32x16_bf16(afrag, bfr[ks], acc[jf], 0, 0, 0);
      }
      // depth-2 lookahead cap: fence after odd ks only (32-reg window)
      if (ks & 1) __builtin_amdgcn_sched_barrier(0);
    }
    // lane holds z[row][j] (incl. bias), j = jf*32 + 8q + 4hi + e

    if (s < 2) {
      __syncthreads();   // all wbuf(s) reads done
      issue_w(s + 1);    // overlaps with stats + normalize below
    }

    // LN stats -- packed f32x2 (v_pk_add / v_pk_fma)
    f32x2 s1v = {0.f, 0.f}, s2v = {0.f, 0.f};
    #pragma unroll
    for (int jf = 0; jf < 4; ++jf) {
      f32x16p az = __builtin_bit_cast(f32x16p, acc[jf]);
      f32x2 p1 = {0.f, 0.f}, p2 = {0.f, 0.f};
      #pragma unroll
      for (int e = 0; e < 8; ++e) {
        f32x2 v = az.h[e];
        p1 += v;
        p2 = __builtin_elementwise_fma(v, v, p2);
      }
      s1v += p1; s2v += p2;
    }
    float s1 = s1v[0] + s1v[1];
    float s2 = s2v[0] + s2v[1];
    s1 += __shfl_xor(s1, 32, 64);
    s2 += __shfl_xor(s2, 32, 64);
    float mean = s1 * 0.0078125f;
    float var = s2 * 0.0078125f - mean * mean;
    float rstd = rsqrtf(var + 1e-5f);
    float nmr = -mean * rstd;
    const f32x2 rstd2 = {rstd, rstd};
    const f32x2 nmr2 = {nmr, nmr};

    if (s < 2) {
      // normalize + ssp-core in ks-order (packed affine, scalar trans)
      #pragma unroll
      for (int ks = 0; ks < 8; ++ks) {
        int jf = ks >> 1, q0 = (ks & 1) << 1;
        f32x16p az = __builtin_bit_cast(f32x16p, acc[jf]);
        uint2 wq[2];
        #pragma unroll
        for (int qq = 0; qq < 2; ++qq) {
          int q = q0 + qq;
          f32x4p g = __builtin_bit_cast(f32x4p, cball[s * 3 + 1][jf * 8 + 2 * q + (int)hi]);
          f32x4p t = __builtin_bit_cast(f32x4p, cball[s * 3 + 2][jf * 8 + 2 * q + (int)hi]);
          f32x2 u0 = __builtin_elementwise_fma(az.h[2 * q + 0], rstd2, nmr2);
          f32x2 u1 = __builtin_elementwise_fma(az.h[2 * q + 1], rstd2, nmr2);
          f32x2 x0 = __builtin_elementwise_fma(u0, g.h[0], t.h[0]);
          f32x2 x1 = __builtin_elementwise_fma(u1, g.h[1], t.h[1]);
          wq[qq].x = pk2(l2p1e(x0[0]), l2p1e(x0[1]));
          wq[qq].y = pk2(l2p1e(x1[0]), l2p1e(x1[1]));
        }
        // exchange across lane pair -> next-stage B-fragment
        u32 sx = hi ? wq[0].x : wq[1].x;
        u32 sy = hi ? wq[0].y : wq[1].y;
        u32 rx = (u32)__shfl_xor((int)sx, 32, 64);
        u32 ry = (u32)__shfl_xor((int)sy, 32, 64);
        u32x4 tq;
        tq.x = hi ? rx : wq[0].x;       // h=0 quad (j offset 0..3)
        tq.y = hi ? ry : wq[0].y;
        tq.z = hi ? wq[1].x : rx;       // h=1 quad (j offset 4..7)
        tq.w = hi ? wq[1].y : ry;
        bfr[ks] = __builtin_bit_cast(bf16x8, tq);
      }
    } else {
      // final stage: fused projection (packed affine, scalar trans+proj)
      float pa = 0.f, pb2 = 0.f;
      #pragma unroll
      for (int jf = 0; jf < 4; ++jf) {
        f32x16p az = __builtin_bit_cast(f32x16p, acc[jf]);
        #pragma unroll
        for (int q = 0; q < 4; ++q) {
          f32x4 g4 = cball[7][jf * 8 + 2 * q + (int)hi];
          f32x4 t4 = cball[8][jf * 8 + 2 * q + (int)hi];
          f32x4 w4 = cball[9][jf * 8 + 2 * q + (int)hi];
          f32x4p g = __builtin_bit_cast(f32x4p, g4);
          f32x4p t = __builtin_bit_cast(f32x4p, t4);
          f32x2 u0 = __builtin_elementwise_fma(az.h[2 * q + 0], rstd2, nmr2);
          f32x2 u1 = __builtin_elementwise_fma(az.h[2 * q + 1], rstd2, nmr2);
          f32x2 x0 = __builtin_elementwise_fma(u0, g.h[0], t.h[0]);
          f32x2 x1 = __builtin_elementwise_fma(u1, g.h[1], t.h[1]);
          pa = __builtin_fmaf(l2p1e(x0[0]), w4[0], pa);
          pb2 = __builtin_fmaf(l2p1e(x0[1]), w4[1], pb2);
          pa = __builtin_fmaf(l2p1e(x1[0]), w4[2], pa);
          pb2 = __builtin_fmaf(l2p1e(x1[1]), w4[3], pb2);
        }
      }
      pfin = pa + pb2;
    }
  }

  // ---- segment sum ----
  pfin += __shfl_xor(pfin, 32, 64);   // combine the two j-halves of this row
  if (grow < nrows) {                  // wave-uniform (32 | nrows)
    pfin += c0s;                       // per-row constant from ssp fold
    int cell;
    if (is_proc) {
      int tt = grow / NN;
      cell = tt * 1024 + batch[grow - tt * NN];
    } else {
      cell = batch[grow];
    }
    // batch sorted -> cells monotone within the 32 consecutive rows
    int ca = __shfl(cell, 0, 32);
    int cz = __shfl(cell, 31, 32);
    if (ca == cz) {
      float r = pfin;
      #pragma unroll
      for (int off = 1; off < 32; off <<= 1) r += __shfl_xor(r, off, 64);
      if (hi == 0) {
        if (is_proc) {
          if (l31 == 0) atomicAdd(out + ca, r);
        } else {
          if (l31 < 4) atomicAdd(out + l31 * 1024 + ca, r);  // enc adds to all 4 t
        }
      }
    } else if (hi == 0) {
      if (is_proc) {
        atomicAdd(out + cell, pfin);
      } else {
        #pragma unroll
        for (int t2 = 0; t2 < 4; ++t2) atomicAdd(out + t2 * 1024 + cell, pfin);
      }
    }
  }
}

extern "C" void kernel_launch(void* const* d_in, const int* in_sizes, int n_in,
                              void* d_out, int out_size, void* d_ws, size_t ws_size,
                              hipStream_t stream) {
  const float* x_proc = (const float*)d_in[0];
  const float* x_enc  = (const float*)d_in[1];
  const int*   batch  = (const int*)d_in[2];
  const float* pW  = (const float*)d_in[3];
  const float* pb  = (const float*)d_in[4];
  const float* pg  = (const float*)d_in[5];
  const float* pbt = (const float*)d_in[6];
  const float* eW  = (const float*)d_in[7];
  const float* eb  = (const float*)d_in[8];
  const float* eg  = (const float*)d_in[9];
  const float* ebt = (const float*)d_in[10];
  const float* wp  = (const float*)d_in[11];
  const float* bp  = (const float*)d_in[12];
  const float* we  = (const float*)d_in[13];
  const float* be  = (const float*)d_in[14];

  float* out = (float*)d_out;
  u16* wt_ws = (u16*)d_ws;                       // 196608 B swizzled W images
  float* cprep = (float*)((char*)d_ws + 196608); // 2*CSTRIDE floats of folded consts

  prep_kernel<<<386, 256, 0, stream>>>(pW, eW, pb, pg, pbt, eb, eg, ebt,
                                       wp, we, bp, be, wt_ws, cprep, out);
  mlp_kernel<<<NPROC_BLOCKS + NENC_BLOCKS, 256, 0, stream>>>(
      x_proc, x_enc, wt_ws, cprep, batch, out);
}